// Round 1
// baseline (531.321 us; speedup 1.0000x reference)
//
#include <hip/hip_runtime.h>
#include <hip/hip_cooperative_groups.h>
#include <stdint.h>

namespace cg = cooperative_groups;

// Problem constants
#define QP 127.0f
#define HW2 50176            // 224*224
#define NPIX 1605632         // 32*224*224
#define NELEM 25690112       // 32*16*224*224
#define NTILES 1568          // 32 n * 7*7 tiles of 32x32

// ---- workspace layout (bytes) ----
// shared by both paths:
#define WS_WQ    256         // 576 dwords packed weights
#define WS_XQ    (1 << 20)   // NPIX * 16B of cin-packed int8 activations
// old (fallback) path:
#define WS_PART  4096        // 1568*32 floats of per-block stat partials
// mega path:
#define MWS_BMAX 4096        // gridDim floats of per-block |x| maxima
#define MWS_PART 16384       // 1568*32 floats of per-tile stat partials

__device__ __forceinline__ int dot4(int a, int b, int c) {
#if defined(__has_builtin) && __has_builtin(__builtin_amdgcn_sdot4)
  return __builtin_amdgcn_sdot4(a, b, c, false);
#else
  int r = c;
  r += (int)(signed char)(a)       * (int)(signed char)(b);
  r += (int)(signed char)(a >> 8)  * (int)(signed char)(b >> 8);
  r += (int)(signed char)(a >> 16) * (int)(signed char)(b >> 16);
  r += (a >> 24) * (b >> 24);
  return r;
#endif
}

// Shared int8 conv core: 4 consecutive rows x 16 cout per thread.
// kw loop NOT unrolled (full unroll -> spill). Weights via uniform-index
// loads -> SGPRs.
__device__ __forceinline__ void conv_core(const int4* sX, const int4* wq4,
                                          int tx, int ty, int (&acc)[4][16]) {
  #pragma unroll
  for (int p = 0; p < 4; ++p)
    #pragma unroll
    for (int c = 0; c < 16; ++c) acc[p][c] = 0;

  #pragma unroll 1
  for (int kw = 0; kw < 3; ++kw) {
    int4 xr[6];                                      // sX rows ty*4 .. ty*4+5
    #pragma unroll
    for (int j = 0; j < 6; ++j) xr[j] = sX[(ty * 4 + j) * 34 + tx + kw];
    #pragma unroll
    for (int c = 0; c < 16; ++c) {
      #pragma unroll
      for (int kh = 0; kh < 3; ++kh) {
        int4 wv = wq4[(c * 3 + kh) * 3 + kw];
        #pragma unroll
        for (int p = 0; p < 4; ++p) {
          int4 xv = xr[p + kh];
          int a = acc[p][c];
          a = dot4(xv.x, wv.x, a);
          a = dot4(xv.y, wv.y, a);
          a = dot4(xv.z, wv.z, a);
          a = dot4(xv.w, wv.w, a);
          acc[p][c] = a;
        }
      }
    }
  }
}

// ======================= cooperative mega-kernel =======================
// Phase A: absmax(x) per block -> bmax[]; block 0 quantizes weights. sync.
// Phase B: per tile: load float x tile+halo (L3-hot), quantize in-reg
//          (same rintf(v/sx) math), store packed interior xq, conv, stats
//          partials. sync.
// Phase C: every block redundantly reduces partials (double, identical
//          order -> identical bits), then output conv pass from xq.
__global__ __launch_bounds__(256, 4) void k_mega(
    const float* __restrict__ x, const float* __restrict__ w,
    const float* __restrict__ gamma, const float* __restrict__ beta,
    float* __restrict__ out, char* __restrict__ ws) {
  __shared__ int4 sX[34 * 34];                       // 18496 B; aliased below
  __shared__ float sRedS[4][16];
  __shared__ float sRedQ[4][16];
  __shared__ float sRed4[4];
  __shared__ float sAB[32];                          // A[16], B[16]

  float* hdr_f = (float*)ws;                         // [0] = sw
  int* wqd = (int*)(ws + WS_WQ);
  const int4* wq4 = (const int4*)(ws + WS_WQ);
  float* bmax = (float*)(ws + MWS_BMAX);
  float* partials = (float*)(ws + MWS_PART);
  int4* xq = (int4*)(ws + WS_XQ);

  const int tid = threadIdx.x;
  const int G = gridDim.x;

  // ---------------- Phase A: absmax(x) + weight quant ----------------
  {
    const float4* x4 = (const float4*)x;
    float m = 0.0f;
    for (int i = blockIdx.x * 256 + tid; i < NELEM / 4; i += G * 256) {
      float4 v = x4[i];
      m = fmaxf(m, fmaxf(fmaxf(fabsf(v.x), fabsf(v.y)),
                         fmaxf(fabsf(v.z), fabsf(v.w))));
    }
    #pragma unroll
    for (int off = 32; off; off >>= 1) m = fmaxf(m, __shfl_down(m, off, 64));
    if ((tid & 63) == 0) sRed4[tid >> 6] = m;
    __syncthreads();
    if (tid == 0)
      bmax[blockIdx.x] =
          fmaxf(fmaxf(sRed4[0], sRed4[1]), fmaxf(sRed4[2], sRed4[3]));

    if (blockIdx.x == 0) {
      __syncthreads();                               // sRed4 reuse
      float mw = 0.0f;
      for (int i = tid; i < 2304; i += 256) mw = fmaxf(mw, fabsf(w[i]));
      #pragma unroll
      for (int off = 32; off; off >>= 1) mw = fmaxf(mw, __shfl_down(mw, off, 64));
      if ((tid & 63) == 0) sRed4[tid >> 6] = mw;
      __syncthreads();
      float sw = fmaxf(fmaxf(sRed4[0], sRed4[1]), fmaxf(sRed4[2], sRed4[3])) / QP;
      if (tid == 0) hdr_f[0] = sw;
      // pack: wq[(cout*9 + kh*3+kw)*4 + c4], byte j of dword = cin 4*c4+j
      for (int i = tid; i < 576; i += 256) {
        int cout = i / 36; int r = i - cout * 36;
        int tap = r >> 2;  int c4 = r & 3;
        int kh = tap / 3, kw2 = tap - kh * 3;
        unsigned bits = 0;
        #pragma unroll
        for (int j = 0; j < 4; ++j) {
          int cin = c4 * 4 + j;
          float v = w[((cout * 16 + cin) * 3 + kh) * 3 + kw2];
          int q = (int)rintf(v / sw);                // rint = round-half-even
          q = max(-127, min(127, q));
          bits |= ((unsigned)(q & 0xff)) << (8 * j);
        }
        wqd[i] = (int)bits;
      }
    }
  }
  cg::this_grid().sync();

  // ---------------- Phase B: quantize-on-stage + stats conv ----------------
  __syncthreads();                                   // sRed4 reuse across phases
  float m2 = 0.0f;
  for (int i = tid; i < G; i += 256) m2 = fmaxf(m2, bmax[i]);
  #pragma unroll
  for (int off = 32; off; off >>= 1) m2 = fmaxf(m2, __shfl_down(m2, off, 64));
  if ((tid & 63) == 0) sRed4[tid >> 6] = m2;
  __syncthreads();
  const float sx =
      fmaxf(fmaxf(sRed4[0], sRed4[1]), fmaxf(sRed4[2], sRed4[3])) / QP;

  const int tx = tid & 31, ty = tid >> 5;

  for (int tile = blockIdx.x; tile < NTILES; tile += G) {
    int n = tile / 49; int r = tile - n * 49;
    int t_y = r / 7, t_x = r - t_y * 7;
    int h0 = t_y * 32, w0 = t_x * 32;

    // stage + quantize (x is L3-resident after phase A)
    for (int i = tid; i < 34 * 34; i += 256) {
      int row = i / 34, col = i - row * 34;
      int gh = h0 - 1 + row, gw = w0 - 1 + col;
      int4 v = {0, 0, 0, 0};
      if ((unsigned)gh < 224u && (unsigned)gw < 224u) {
        const float* xp = x + (size_t)n * 16 * HW2 + gh * 224 + gw;
        unsigned comp[4] = {0u, 0u, 0u, 0u};
        #pragma unroll
        for (int c = 0; c < 16; ++c) {
          float f = xp[(size_t)c * HW2];
          int q = (int)rintf(f / sx);                // f32 div, matches ref
          q = max(-127, min(127, q));
          comp[c >> 2] |= ((unsigned)(q & 0xff)) << (8 * (c & 3));
        }
        v.x = (int)comp[0]; v.y = (int)comp[1];
        v.z = (int)comp[2]; v.w = (int)comp[3];
        if (row >= 1 && row <= 32 && col >= 1 && col <= 32)
          xq[(n * 224 + gh) * 224 + gw] = v;         // by-product for phase C
      }
      sX[i] = v;
    }
    __syncthreads();

    int acc[4][16];
    conv_core(sX, wq4, tx, ty, acc);

    // stats epilogue: LDS transpose (stride 257, conflict-free) + shuffles
    float* sR = (float*)sX;
    int wv_ = tid >> 6, seg = tid >> 4, cc = tid & 15;
    __syncthreads();                                 // all sX reads done
    #pragma unroll
    for (int c = 0; c < 16; ++c) {
      int si = acc[0][c] + acc[1][c] + acc[2][c] + acc[3][c];
      sR[c * 257 + tid] = (float)si;
    }
    __syncthreads();
    {
      float ps = 0.0f;
      #pragma unroll
      for (int j = 0; j < 16; ++j) ps += sR[cc * 257 + (seg & 3) * 16 + j];
      ps += __shfl_xor(ps, 16, 64);
      ps += __shfl_xor(ps, 32, 64);
      if ((tid & 63) < 16) sRedS[wv_][cc] = ps;
    }
    __syncthreads();
    #pragma unroll
    for (int c = 0; c < 16; ++c) {
      float f0 = (float)acc[0][c], f1 = (float)acc[1][c];
      float f2 = (float)acc[2][c], f3 = (float)acc[3][c];
      sR[c * 257 + tid] = f0 * f0 + f1 * f1 + f2 * f2 + f3 * f3;
    }
    __syncthreads();
    {
      float pq = 0.0f;
      #pragma unroll
      for (int j = 0; j < 16; ++j) pq += sR[cc * 257 + (seg & 3) * 16 + j];
      pq += __shfl_xor(pq, 16, 64);
      pq += __shfl_xor(pq, 32, 64);
      if ((tid & 63) < 16) sRedQ[wv_][cc] = pq;
    }
    __syncthreads();
    if (tid < 32) {
      int c = tid & 15;
      float t;
      if (tid < 16) t = sRedS[0][c] + sRedS[1][c] + sRedS[2][c] + sRedS[3][c];
      else          t = sRedQ[0][c] + sRedQ[1][c] + sRedQ[2][c] + sRedQ[3][c];
      partials[tile * 32 + tid] = t;
    }
    __syncthreads();                                 // protect LDS for next tile
  }
  cg::this_grid().sync();

  // ---------------- Phase C: redundant finalize + output conv ----------------
  {
    double* sdd = (double*)sX;                       // [256][4] = 8192 B
    double* sfin = ((double*)sX) + 1024;             // 32 doubles, bytes 8192..8448
    const float4* p4 = (const float4*)partials;      // 12544 float4s
    double d0 = 0, d1 = 0, d2 = 0, d3 = 0;
    #pragma unroll 7
    for (int k = 0; k < 49; ++k) {
      float4 v = p4[tid + 256 * k];
      d0 += (double)v.x; d1 += (double)v.y; d2 += (double)v.z; d3 += (double)v.w;
    }
    sdd[tid * 4 + 0] = d0; sdd[tid * 4 + 1] = d1;
    sdd[tid * 4 + 2] = d2; sdd[tid * 4 + 3] = d3;
    __syncthreads();
    if (tid < 32) {
      double s = 0.0;
      #pragma unroll 8
      for (int i = 0; i < 32; ++i) s += sdd[((tid >> 2) + 8 * i) * 4 + (tid & 3)];
      sfin[tid] = s;
    }
    __syncthreads();
    if (tid < 16) {
      float sf = sx * hdr_f[0];                      // combined dequant scale (f32)
      double s = (double)sf;
      const double M = (double)NPIX;
      double mean = s * sfin[tid] / M;
      double ey2 = s * s * sfin[16 + tid] / M;
      double var = ey2 - mean * mean;                // biased var, matches jnp.var
      double inv = (double)gamma[tid] / sqrt(var + 1e-5);
      sAB[tid] = (float)(s * inv);                   // A
      sAB[16 + tid] = (float)((double)beta[tid] - mean * inv);  // B
    }
    __syncthreads();
  }

  for (int tile = blockIdx.x; tile < NTILES; tile += G) {
    int n = tile / 49; int r = tile - n * 49;
    int t_y = r / 7, t_x = r - t_y * 7;
    int h0 = t_y * 32, w0 = t_x * 32;

    for (int i = tid; i < 34 * 34; i += 256) {
      int row = i / 34, col = i - row * 34;
      int gh = h0 - 1 + row, gw = w0 - 1 + col;
      int4 v = {0, 0, 0, 0};
      if ((unsigned)gh < 224u && (unsigned)gw < 224u)
        v = xq[(n * 224 + gh) * 224 + gw];
      sX[i] = v;
    }
    __syncthreads();

    int acc[4][16];
    conv_core(sX, wq4, tx, ty, acc);

    #pragma unroll
    for (int c = 0; c < 16; ++c) {
      float A = sAB[c], B = sAB[16 + c];
      #pragma unroll
      for (int p = 0; p < 4; ++p) {
        float y = fmaf((float)acc[p][c], A, B);
        y = fminf(fmaxf(y, 0.0f), 6.0f);
        out[((n * 16 + c) * 224 + (h0 + ty * 4 + p)) * 224 + (w0 + tx)] = y;
      }
    }
    __syncthreads();                                 // protect sX for next tile
  }
}

// ======================= fallback path (previous verified kernels) =======================
__global__ void k_quant_w(const float* __restrict__ w, char* __restrict__ ws) {
  unsigned* hdr_u = (unsigned*)ws;
  float* hdr_f = (float*)ws;
  int* wq = (int*)(ws + WS_WQ);
  if (threadIdx.x == 0) hdr_u[0] = 0u;               // absmax accumulator
  float m = 0.0f;
  for (int i = threadIdx.x; i < 2304; i += 256) m = fmaxf(m, fabsf(w[i]));
  #pragma unroll
  for (int off = 32; off; off >>= 1) m = fmaxf(m, __shfl_down(m, off, 64));
  __shared__ float red[4];
  __shared__ float s_sw;
  if ((threadIdx.x & 63) == 0) red[threadIdx.x >> 6] = m;
  __syncthreads();
  if (threadIdx.x == 0) {
    float mw = fmaxf(fmaxf(red[0], red[1]), fmaxf(red[2], red[3]));
    float sw = mw / QP;
    hdr_f[1] = sw;
    s_sw = sw;
  }
  __syncthreads();
  float sw = s_sw;
  for (int i = threadIdx.x; i < 576; i += 256) {
    int cout = i / 36; int r = i - cout * 36;
    int tap = r >> 2;  int c4 = r & 3;
    int kh = tap / 3, kw = tap - kh * 3;
    unsigned bits = 0;
    #pragma unroll
    for (int j = 0; j < 4; ++j) {
      int cin = c4 * 4 + j;
      float v = w[((cout * 16 + cin) * 3 + kh) * 3 + kw];
      int q = (int)rintf(v / sw);
      q = max(-127, min(127, q));
      bits |= ((unsigned)(q & 0xff)) << (8 * j);
    }
    wq[i] = (int)bits;
  }
}

__global__ void k_absmax(const float* __restrict__ x, unsigned* __restrict__ absmax_bits) {
  const float4* x4 = (const float4*)x;
  const int n4 = NELEM / 4;
  float m = 0.0f;
  for (int i = blockIdx.x * blockDim.x + threadIdx.x; i < n4; i += gridDim.x * blockDim.x) {
    float4 v = x4[i];
    m = fmaxf(m, fmaxf(fmaxf(fabsf(v.x), fabsf(v.y)), fmaxf(fabsf(v.z), fabsf(v.w))));
  }
  #pragma unroll
  for (int off = 32; off; off >>= 1) m = fmaxf(m, __shfl_down(m, off, 64));
  __shared__ float red[4];
  int lane = threadIdx.x & 63, wv = threadIdx.x >> 6;
  if (lane == 0) red[wv] = m;
  __syncthreads();
  if (threadIdx.x == 0) {
    m = fmaxf(fmaxf(red[0], red[1]), fmaxf(red[2], red[3]));
    atomicMax(absmax_bits, __float_as_uint(m));
  }
}

__global__ void k_quant_x(const float* __restrict__ x, char* __restrict__ ws) {
  const unsigned* hdr_u = (const unsigned*)ws;
  int4* xq = (int4*)(ws + WS_XQ);
  float sx = __uint_as_float(hdr_u[0]) / QP;
  int t = blockIdx.x * 256 + threadIdx.x;
  int p0 = t * 4;
  int n = p0 / HW2;
  int hw = p0 - n * HW2;
  const float4* xb = (const float4*)(x + (size_t)n * 16 * HW2 + hw);
  unsigned comp[4][4];
  #pragma unroll
  for (int j = 0; j < 4; ++j)
    #pragma unroll
    for (int k = 0; k < 4; ++k) comp[j][k] = 0u;
  #pragma unroll
  for (int c = 0; c < 16; ++c) {
    float4 vc = xb[c * (HW2 / 4)];
    float f[4] = {vc.x, vc.y, vc.z, vc.w};
    #pragma unroll
    for (int j = 0; j < 4; ++j) {
      int q = (int)rintf(f[j] / sx);
      q = max(-127, min(127, q));
      comp[j][c >> 2] |= ((unsigned)(q & 0xff)) << (8 * (c & 3));
    }
  }
  #pragma unroll
  for (int j = 0; j < 4; ++j) {
    int4 v;
    v.x = (int)comp[j][0]; v.y = (int)comp[j][1];
    v.z = (int)comp[j][2]; v.w = (int)comp[j][3];
    xq[p0 + j] = v;
  }
}

template <bool WRITE_OUT>
__global__ __launch_bounds__(256) void k_conv(const char* __restrict__ ws,
                                              float* __restrict__ out,
                                              float* __restrict__ partials) {
  const int4* __restrict__ xq = (const int4*)(ws + WS_XQ);
  const int4* __restrict__ wq4 = (const int4*)(ws + WS_WQ);
  __shared__ int4 sX[34 * 34];
  __shared__ float sRedS[4][16];
  __shared__ float sRedQ[4][16];

  int tid = threadIdx.x;
  int b = blockIdx.x;
  int n = b / 49; int r = b - n * 49;
  int t_y = r / 7, t_x = r - t_y * 7;
  int h0 = t_y * 32, w0 = t_x * 32;

  for (int i = tid; i < 34 * 34; i += 256) {
    int row = i / 34, col = i - row * 34;
    int gh = h0 - 1 + row, gw = w0 - 1 + col;
    int4 v = {0, 0, 0, 0};
    if ((unsigned)gh < 224u && (unsigned)gw < 224u)
      v = xq[(n * 224 + gh) * 224 + gw];
    sX[i] = v;
  }
  __syncthreads();

  int tx = tid & 31, ty = tid >> 5;
  int acc[4][16];
  conv_core(sX, wq4, tx, ty, acc);

  if (WRITE_OUT) {
    const float* hdr_f = (const float*)ws;
    #pragma unroll
    for (int c = 0; c < 16; ++c) {
      float A = hdr_f[16 + c], B = hdr_f[32 + c];
      #pragma unroll
      for (int p = 0; p < 4; ++p) {
        float y = fmaf((float)acc[p][c], A, B);
        y = fminf(fmaxf(y, 0.0f), 6.0f);
        out[((n * 16 + c) * 224 + (h0 + ty * 4 + p)) * 224 + (w0 + tx)] = y;
      }
    }
  } else {
    float* sR = (float*)sX;
    int wv_ = tid >> 6, seg = tid >> 4, cc = tid & 15;
    __syncthreads();
    #pragma unroll
    for (int c = 0; c < 16; ++c) {
      int si = acc[0][c] + acc[1][c] + acc[2][c] + acc[3][c];
      sR[c * 257 + tid] = (float)si;
    }
    __syncthreads();
    {
      float ps = 0.0f;
      #pragma unroll
      for (int j = 0; j < 16; ++j) ps += sR[cc * 257 + (seg & 3) * 16 + j];
      ps += __shfl_xor(ps, 16, 64);
      ps += __shfl_xor(ps, 32, 64);
      if ((tid & 63) < 16) sRedS[wv_][cc] = ps;
    }
    __syncthreads();
    #pragma unroll
    for (int c = 0; c < 16; ++c) {
      float f0 = (float)acc[0][c], f1 = (float)acc[1][c];
      float f2 = (float)acc[2][c], f3 = (float)acc[3][c];
      sR[c * 257 + tid] = f0 * f0 + f1 * f1 + f2 * f2 + f3 * f3;
    }
    __syncthreads();
    {
      float pq = 0.0f;
      #pragma unroll
      for (int j = 0; j < 16; ++j) pq += sR[cc * 257 + (seg & 3) * 16 + j];
      pq += __shfl_xor(pq, 16, 64);
      pq += __shfl_xor(pq, 32, 64);
      if ((tid & 63) < 16) sRedQ[wv_][cc] = pq;
    }
    __syncthreads();
    if (tid < 32) {
      int c = tid & 15;
      float t;
      if (tid < 16) t = sRedS[0][c] + sRedS[1][c] + sRedS[2][c] + sRedS[3][c];
      else          t = sRedQ[0][c] + sRedQ[1][c] + sRedQ[2][c] + sRedQ[3][c];
      partials[b * 32 + tid] = t;
    }
  }
}

__global__ void k_finalize(const float* __restrict__ partials,
                           const float* __restrict__ gamma,
                           const float* __restrict__ beta,
                           float* __restrict__ hdr_f) {
  const unsigned* hdr_u = (const unsigned*)hdr_f;
  __shared__ double sdd[256][4];
  __shared__ double sfin[32];
  int t = threadIdx.x;
  const float4* p4 = (const float4*)partials;
  double d0 = 0, d1 = 0, d2 = 0, d3 = 0;
  #pragma unroll 7
  for (int k = 0; k < 49; ++k) {
    float4 v = p4[t + 256 * k];
    d0 += (double)v.x; d1 += (double)v.y; d2 += (double)v.z; d3 += (double)v.w;
  }
  sdd[t][0] = d0; sdd[t][1] = d1; sdd[t][2] = d2; sdd[t][3] = d3;
  __syncthreads();
  if (t < 32) {
    double s = 0.0;
    #pragma unroll 8
    for (int i = 0; i < 32; ++i) s += sdd[(t >> 2) + 8 * i][t & 3];
    sfin[t] = s;
  }
  __syncthreads();
  if (t < 16) {
    float sxf = __uint_as_float(hdr_u[0]) / QP;
    float sf = sxf * hdr_f[1];
    double s = (double)sf;
    const double M = (double)NPIX;
    double mean = s * sfin[t] / M;
    double ey2 = s * s * sfin[16 + t] / M;
    double var = ey2 - mean * mean;
    double inv = (double)gamma[t] / sqrt(var + 1e-5);
    hdr_f[16 + t] = (float)(s * inv);
    hdr_f[32 + t] = (float)((double)beta[t] - mean * inv);
  }
}

extern "C" void kernel_launch(void* const* d_in, const int* in_sizes, int n_in,
                              void* d_out, int out_size, void* d_ws, size_t ws_size,
                              hipStream_t stream) {
  const float* x = (const float*)d_in[0];
  const float* w = (const float*)d_in[1];
  const float* gamma = (const float*)d_in[2];
  const float* beta = (const float*)d_in[3];
  float* out = (float*)d_out;
  char* ws = (char*)d_ws;

  // Decide cooperative grid once: grid = min(occ_blocks_per_cu * 256 CU, NTILES)
  static int s_grid = 0;                             // 0 = unknown, -1 = fallback
  if (s_grid == 0) {
    int occ = 0;
    hipError_t e = hipOccupancyMaxActiveBlocksPerMultiprocessor(&occ, k_mega, 256, 0);
    if (e != hipSuccess || occ < 1) {
      s_grid = -1;
      (void)hipGetLastError();
    } else {
      int g = occ * 256;                             // MI355X: 256 CUs
      if (g > NTILES) g = NTILES;
      s_grid = g;
    }
  }

  bool done = false;
  if (s_grid > 0) {
    void* args[] = {(void*)&x, (void*)&w, (void*)&gamma, (void*)&beta,
                    (void*)&out, (void*)&ws};
    hipError_t e = hipLaunchCooperativeKernel(k_mega, dim3(s_grid), dim3(256),
                                              args, 0u, stream);
    if (e == hipSuccess) {
      done = true;
    } else {
      s_grid = -1;                                   // permanent fallback
      (void)hipGetLastError();                       // clear sticky error
    }
  }

  if (!done) {
    k_quant_w<<<1, 256, 0, stream>>>(w, ws);
    k_absmax<<<2048, 256, 0, stream>>>(x, (unsigned*)ws);
    k_quant_x<<<1568, 256, 0, stream>>>(x, ws);
    k_conv<false><<<1568, 256, 0, stream>>>(ws, nullptr, (float*)(ws + WS_PART));
    k_finalize<<<1, 256, 0, stream>>>((const float*)(ws + WS_PART), gamma, beta, (float*)ws);
    k_conv<true><<<1568, 256, 0, stream>>>(ws, out, nullptr);
  }
}

// Round 2
// 317.356 us; speedup vs baseline: 1.6742x; 1.6742x over previous
//
#include <hip/hip_runtime.h>
#include <stdint.h>

// Problem constants
#define QP 127.0f
#define HW2 50176            // 224*224
#define NPIX 1605632         // 32*224*224
#define NELEM 25690112       // 32*16*224*224
#define NTILES 1568          // 32 n * 7*7 tiles of 32x32
#define ABS_GRID 2048        // k_absmax_wq grid (fixed; bmax sized for it)

// ---- workspace layout (bytes) ----
#define WS_WQ    256         // 576 dwords packed weights (2304 B)
#define WS_BMAX  4096        // ABS_GRID floats of per-block |x| maxima (8 KB)
#define WS_PART  16384       // 1568*32 floats of per-tile stat partials (200 KB)
#define WS_XQ    (1 << 20)   // NPIX * 16B of cin-packed int8 activations
// hdr floats: hdr_f[1] = sw (weight scale), hdr_f[2] = sx (act scale)

__device__ __forceinline__ int dot4(int a, int b, int c) {
#if defined(__has_builtin) && __has_builtin(__builtin_amdgcn_sdot4)
  return __builtin_amdgcn_sdot4(a, b, c, false);
#else
  int r = c;
  r += (int)(signed char)(a)       * (int)(signed char)(b);
  r += (int)(signed char)(a >> 8)  * (int)(signed char)(b >> 8);
  r += (int)(signed char)(a >> 16) * (int)(signed char)(b >> 16);
  r += (a >> 24) * (b >> 24);
  return r;
#endif
}

// Shared int8 conv core: 4 consecutive rows x 16 cout per thread.
// kw loop NOT unrolled (full unroll -> spill). Weights via uniform-index
// loads -> SGPRs. Verified (baseline R5 + mega numerics).
__device__ __forceinline__ void conv_core(const int4* sX, const int4* wq4,
                                          int tx, int ty, int (&acc)[4][16]) {
  #pragma unroll
  for (int p = 0; p < 4; ++p)
    #pragma unroll
    for (int c = 0; c < 16; ++c) acc[p][c] = 0;

  #pragma unroll 1
  for (int kw = 0; kw < 3; ++kw) {
    int4 xr[6];                                      // sX rows ty*4 .. ty*4+5
    #pragma unroll
    for (int j = 0; j < 6; ++j) xr[j] = sX[(ty * 4 + j) * 34 + tx + kw];
    #pragma unroll
    for (int c = 0; c < 16; ++c) {
      #pragma unroll
      for (int kh = 0; kh < 3; ++kh) {
        int4 wv = wq4[(c * 3 + kh) * 3 + kw];
        #pragma unroll
        for (int p = 0; p < 4; ++p) {
          int4 xv = xr[p + kh];
          int a = acc[p][c];
          a = dot4(xv.x, wv.x, a);
          a = dot4(xv.y, wv.y, a);
          a = dot4(xv.z, wv.z, a);
          a = dot4(xv.w, wv.w, a);
          acc[p][c] = a;
        }
      }
    }
  }
}

// ---------------- D1: absmax(x) per block + weight quant in block 0 ----------------
// No atomics / no header zeroing race: block b writes bmax[b]; D2 reduces.
__global__ __launch_bounds__(256) void k_absmax_wq(const float* __restrict__ x,
                                                   const float* __restrict__ w,
                                                   char* __restrict__ ws) {
  __shared__ float red[4];
  __shared__ float s_sw;
  float* hdr_f = (float*)ws;
  float* bmax = (float*)(ws + WS_BMAX);
  int* wq = (int*)(ws + WS_WQ);
  const int tid = threadIdx.x;

  const float4* x4 = (const float4*)x;
  float m = 0.0f;
  for (int i = blockIdx.x * 256 + tid; i < NELEM / 4; i += ABS_GRID * 256) {
    float4 v = x4[i];
    m = fmaxf(m, fmaxf(fmaxf(fabsf(v.x), fabsf(v.y)),
                       fmaxf(fabsf(v.z), fabsf(v.w))));
  }
  #pragma unroll
  for (int off = 32; off; off >>= 1) m = fmaxf(m, __shfl_down(m, off, 64));
  if ((tid & 63) == 0) red[tid >> 6] = m;
  __syncthreads();
  if (tid == 0)
    bmax[blockIdx.x] = fmaxf(fmaxf(red[0], red[1]), fmaxf(red[2], red[3]));

  if (blockIdx.x == 0) {                             // weight quant (verified)
    __syncthreads();                                 // red[] reuse
    float mw = 0.0f;
    for (int i = tid; i < 2304; i += 256) mw = fmaxf(mw, fabsf(w[i]));
    #pragma unroll
    for (int off = 32; off; off >>= 1) mw = fmaxf(mw, __shfl_down(mw, off, 64));
    if ((tid & 63) == 0) red[tid >> 6] = mw;
    __syncthreads();
    if (tid == 0) {
      float sw = fmaxf(fmaxf(red[0], red[1]), fmaxf(red[2], red[3])) / QP;
      hdr_f[1] = sw;
      s_sw = sw;
    }
    __syncthreads();
    float sw = s_sw;
    // pack: wq[(cout*9 + kh*3+kw)*4 + c4], byte j of dword = cin 4*c4+j
    for (int i = tid; i < 576; i += 256) {
      int cout = i / 36; int r = i - cout * 36;
      int tap = r >> 2;  int c4 = r & 3;
      int kh = tap / 3, kw = tap - kh * 3;
      unsigned bits = 0;
      #pragma unroll
      for (int j = 0; j < 4; ++j) {
        int cin = c4 * 4 + j;
        float v = w[((cout * 16 + cin) * 3 + kh) * 3 + kw];
        int q = (int)rintf(v / sw);                  // rint = round-half-even
        q = max(-127, min(127, q));
        bits |= ((unsigned)(q & 0xff)) << (8 * j);
      }
      wq[i] = (int)bits;
    }
  }
}

// ---------------- D2: quantize tile (float4 interior) + stats conv ----------------
// Interior (32x32): k_quant_x's verified float4 pattern, 4 consecutive px/thread,
// written to LDS + xq global. Halo ring (132 px): scalar 16-ch gather (mega-verified
// formula). Then the verified conv + LDS-transpose stats epilogue.
__global__ __launch_bounds__(256) void k_conv_stats_q(const float* __restrict__ x,
                                                      char* __restrict__ ws,
                                                      float* __restrict__ partials) {
  __shared__ int4 sX[34 * 34];                       // 18496 B; aliased below
  __shared__ float sRedS[4][16];
  __shared__ float sRedQ[4][16];
  __shared__ float sRed4[4];

  const int4* __restrict__ wq4 = (const int4*)(ws + WS_WQ);
  const float* __restrict__ bmax = (const float*)(ws + WS_BMAX);
  float* hdr_f = (float*)ws;
  int4* xq = (int4*)(ws + WS_XQ);
  const int tid = threadIdx.x;

  // ---- reduce bmax -> sx (same f32 div-by-QP as verified paths) ----
  float m = 0.0f;
  for (int i = tid; i < ABS_GRID; i += 256) m = fmaxf(m, bmax[i]);
  #pragma unroll
  for (int off = 32; off; off >>= 1) m = fmaxf(m, __shfl_down(m, off, 64));
  if ((tid & 63) == 0) sRed4[tid >> 6] = m;
  __syncthreads();
  const float sx =
      fmaxf(fmaxf(sRed4[0], sRed4[1]), fmaxf(sRed4[2], sRed4[3])) / QP;
  if (blockIdx.x == 0 && tid == 0) hdr_f[2] = sx;    // for D3 finalize

  const int b = blockIdx.x;
  const int n = b / 49; const int r = b - n * 49;
  const int t_y = r / 7, t_x = r - t_y * 7;
  const int h0 = t_y * 32, w0 = t_x * 32;

  // ---- interior quantize: thread t -> row t>>3, cols 4*(t&7)..+3 ----
  {
    int row = tid >> 3, cg = tid & 7;
    int gh = h0 + row, gw0 = w0 + 4 * cg;            // gw0 % 4 == 0: aligned
    const float4* xb = (const float4*)(x + (size_t)n * 16 * HW2 + gh * 224 + gw0);
    unsigned comp[4][4];
    #pragma unroll
    for (int j = 0; j < 4; ++j)
      #pragma unroll
      for (int k = 0; k < 4; ++k) comp[j][k] = 0u;
    #pragma unroll
    for (int c = 0; c < 16; ++c) {
      float4 vc = xb[c * (HW2 / 4)];
      float f[4] = {vc.x, vc.y, vc.z, vc.w};
      #pragma unroll
      for (int j = 0; j < 4; ++j) {
        int q = (int)rintf(f[j] / sx);               // f32 div, matches ref
        q = max(-127, min(127, q));
        comp[j][c >> 2] |= ((unsigned)(q & 0xff)) << (8 * (c & 3));
      }
    }
    #pragma unroll
    for (int j = 0; j < 4; ++j) {
      int4 v;
      v.x = (int)comp[j][0]; v.y = (int)comp[j][1];
      v.z = (int)comp[j][2]; v.w = (int)comp[j][3];
      sX[(row + 1) * 34 + 1 + 4 * cg + j] = v;
      xq[(n * 224 + gh) * 224 + gw0 + j] = v;        // by-product for D3
    }
  }

  // ---- halo quantize: 132 ring pixels, scalar 16-ch gather ----
  if (tid < 132) {
    int row, col;
    if (tid < 34)       { row = 0;                col = tid; }
    else if (tid < 68)  { row = 33;               col = tid - 34; }
    else if (tid < 100) { row = 1 + (tid - 68);   col = 0; }
    else                { row = 1 + (tid - 100);  col = 33; }
    int gh = h0 - 1 + row, gw = w0 - 1 + col;
    int4 v = {0, 0, 0, 0};
    if ((unsigned)gh < 224u && (unsigned)gw < 224u) {
      const float* xp = x + (size_t)n * 16 * HW2 + gh * 224 + gw;
      unsigned comp[4] = {0u, 0u, 0u, 0u};
      #pragma unroll
      for (int c = 0; c < 16; ++c) {
        float f = xp[(size_t)c * HW2];
        int q = (int)rintf(f / sx);
        q = max(-127, min(127, q));
        comp[c >> 2] |= ((unsigned)(q & 0xff)) << (8 * (c & 3));
      }
      v.x = (int)comp[0]; v.y = (int)comp[1];
      v.z = (int)comp[2]; v.w = (int)comp[3];
    }
    sX[row * 34 + col] = v;
  }
  __syncthreads();

  const int tx = tid & 31, ty = tid >> 5;
  int acc[4][16];
  conv_core(sX, wq4, tx, ty, acc);

  // ---- stats epilogue: LDS transpose (stride 257, conflict-free) + shuffles ----
  float* sR = (float*)sX;
  int wv_ = tid >> 6, seg = tid >> 4, cc = tid & 15;
  __syncthreads();                                   // all sX reads done
  #pragma unroll
  for (int c = 0; c < 16; ++c) {
    int si = acc[0][c] + acc[1][c] + acc[2][c] + acc[3][c];  // exact in int32
    sR[c * 257 + tid] = (float)si;
  }
  __syncthreads();
  {
    float ps = 0.0f;
    #pragma unroll
    for (int j = 0; j < 16; ++j) ps += sR[cc * 257 + (seg & 3) * 16 + j];
    ps += __shfl_xor(ps, 16, 64);
    ps += __shfl_xor(ps, 32, 64);
    if ((tid & 63) < 16) sRedS[wv_][cc] = ps;
  }
  __syncthreads();
  #pragma unroll
  for (int c = 0; c < 16; ++c) {
    float f0 = (float)acc[0][c], f1 = (float)acc[1][c];
    float f2 = (float)acc[2][c], f3 = (float)acc[3][c];
    sR[c * 257 + tid] = f0 * f0 + f1 * f1 + f2 * f2 + f3 * f3;
  }
  __syncthreads();
  {
    float pq = 0.0f;
    #pragma unroll
    for (int j = 0; j < 16; ++j) pq += sR[cc * 257 + (seg & 3) * 16 + j];
    pq += __shfl_xor(pq, 16, 64);
    pq += __shfl_xor(pq, 32, 64);
    if ((tid & 63) < 16) sRedQ[wv_][cc] = pq;
  }
  __syncthreads();
  if (tid < 32) {
    int c = tid & 15;
    float t;
    if (tid < 16) t = sRedS[0][c] + sRedS[1][c] + sRedS[2][c] + sRedS[3][c];
    else          t = sRedQ[0][c] + sRedQ[1][c] + sRedQ[2][c] + sRedQ[3][c];
    partials[b * 32 + tid] = t;
  }
}

// ---------------- D3: redundant finalize prologue + output conv ----------------
// Every block reduces partials identically (double, identical order -> identical
// A,B bits; mega-verified). Removes the single-block k_finalize dispatch.
__global__ __launch_bounds__(256) void k_conv_out(const char* __restrict__ ws,
                                                  const float* __restrict__ gamma,
                                                  const float* __restrict__ beta,
                                                  const float* __restrict__ partials,
                                                  float* __restrict__ out) {
  __shared__ int4 sX[34 * 34];                       // aliased as double scratch
  __shared__ float sAB[32];                          // A[16], B[16]
  const int4* __restrict__ xq = (const int4*)(ws + WS_XQ);
  const int4* __restrict__ wq4 = (const int4*)(ws + WS_WQ);
  const float* hdr_f = (const float*)ws;
  const int tid = threadIdx.x;

  {
    double* sdd = (double*)sX;                       // [256][4] = 8192 B
    double* sfin = ((double*)sX) + 1024;             // 32 doubles (8192..8448)
    const float4* p4 = (const float4*)partials;      // 12544 float4s
    double d0 = 0, d1 = 0, d2 = 0, d3 = 0;
    #pragma unroll 7
    for (int k = 0; k < 49; ++k) {
      float4 v = p4[tid + 256 * k];
      d0 += (double)v.x; d1 += (double)v.y; d2 += (double)v.z; d3 += (double)v.w;
    }
    sdd[tid * 4 + 0] = d0; sdd[tid * 4 + 1] = d1;
    sdd[tid * 4 + 2] = d2; sdd[tid * 4 + 3] = d3;
    __syncthreads();
    if (tid < 32) {
      double s = 0.0;
      #pragma unroll 8
      for (int i = 0; i < 32; ++i) s += sdd[((tid >> 2) + 8 * i) * 4 + (tid & 3)];
      sfin[tid] = s;
    }
    __syncthreads();
    if (tid < 16) {
      float sf = hdr_f[2] * hdr_f[1];                // sx * sw (f32, as verified)
      double s = (double)sf;
      const double M = (double)NPIX;
      double mean = s * sfin[tid] / M;
      double ey2 = s * s * sfin[16 + tid] / M;
      double var = ey2 - mean * mean;                // biased var, matches jnp.var
      double inv = (double)gamma[tid] / sqrt(var + 1e-5);
      sAB[tid] = (float)(s * inv);                   // A
      sAB[16 + tid] = (float)((double)beta[tid] - mean * inv);  // B
    }
    __syncthreads();                                 // sX reuse below
  }

  const int b = blockIdx.x;
  const int n = b / 49; const int r = b - n * 49;
  const int t_y = r / 7, t_x = r - t_y * 7;
  const int h0 = t_y * 32, w0 = t_x * 32;

  for (int i = tid; i < 34 * 34; i += 256) {
    int row = i / 34, col = i - row * 34;
    int gh = h0 - 1 + row, gw = w0 - 1 + col;
    int4 v = {0, 0, 0, 0};
    if ((unsigned)gh < 224u && (unsigned)gw < 224u)
      v = xq[(n * 224 + gh) * 224 + gw];
    sX[i] = v;
  }
  __syncthreads();

  const int tx = tid & 31, ty = tid >> 5;
  int acc[4][16];
  conv_core(sX, wq4, tx, ty, acc);

  #pragma unroll
  for (int c = 0; c < 16; ++c) {
    float A = sAB[c], B = sAB[16 + c];
    #pragma unroll
    for (int p = 0; p < 4; ++p) {
      float y = fmaf((float)acc[p][c], A, B);
      y = fminf(fmaxf(y, 0.0f), 6.0f);
      out[((n * 16 + c) * 224 + (h0 + ty * 4 + p)) * 224 + (w0 + tx)] = y;
    }
  }
}

extern "C" void kernel_launch(void* const* d_in, const int* in_sizes, int n_in,
                              void* d_out, int out_size, void* d_ws, size_t ws_size,
                              hipStream_t stream) {
  const float* x = (const float*)d_in[0];
  const float* w = (const float*)d_in[1];
  const float* gamma = (const float*)d_in[2];
  const float* beta = (const float*)d_in[3];
  float* out = (float*)d_out;
  char* ws = (char*)d_ws;
  float* partials = (float*)(ws + WS_PART);

  k_absmax_wq<<<ABS_GRID, 256, 0, stream>>>(x, w, ws);
  k_conv_stats_q<<<NTILES, 256, 0, stream>>>(x, ws, partials);
  k_conv_out<<<NTILES, 256, 0, stream>>>(ws, gamma, beta, partials, out);
}

// Round 4
// 282.967 us; speedup vs baseline: 1.8777x; 1.1215x over previous
//
#include <hip/hip_runtime.h>
#include <stdint.h>

// Problem constants
#define QP 127.0f
#define HW2 50176            // 224*224
#define NPIX 1605632         // 32*224*224
#define NELEM 25690112       // 32*16*224*224
#define ABS_GRID 2048        // k_absmax_wq grid (bmax sized for it)
#define NRG 56               // 224/4 row-groups per image
#define NBLK_CONV 1792       // 32 n * 56 row-groups

// ---- workspace layout (bytes) ----
#define WS_WQ    256         // 576 dwords packed weights (2304 B)
#define WS_BMAX  4096        // ABS_GRID floats of per-block |x| maxima (8 KB)
#define WS_PART  16384       // 1792*32 floats of per-block stat partials (229 KB)
#define WS_XQ    (1 << 20)   // NPIX * 16B of cin-packed int8 activations
// hdr floats: hdr_f[1] = sw, hdr_f[2] = sx, hdr_f[16..31] = A, hdr_f[32..47] = B

__device__ __forceinline__ int dot4(int a, int b, int c) {
#if defined(__has_builtin) && __has_builtin(__builtin_amdgcn_sdot4)
  return __builtin_amdgcn_sdot4(a, b, c, false);
#else
  int r = c;
  r += (int)(signed char)(a)       * (int)(signed char)(b);
  r += (int)(signed char)(a >> 8)  * (int)(signed char)(b >> 8);
  r += (int)(signed char)(a >> 16) * (int)(signed char)(b >> 16);
  r += (a >> 24) * (b >> 24);
  return r;
#endif
}

// ---- strip conv core: 4 consecutive rows x 16 cout for column cx ----
// Same math/order as the verified tile conv_core; only LDS addressing differs
// (row stride 226, col offset already includes left pad).
__device__ __forceinline__ void conv_strip(const int4* sXs, const int4* wq4,
                                           int cx, int (&acc)[4][16]) {
  #pragma unroll 1
  for (int kw = 0; kw < 3; ++kw) {
    int4 xr[6];                                      // staged rows 0..5
    #pragma unroll
    for (int j = 0; j < 6; ++j) xr[j] = sXs[j * 226 + cx + kw];
    #pragma unroll
    for (int c = 0; c < 16; ++c) {
      #pragma unroll
      for (int kh = 0; kh < 3; ++kh) {
        int4 wv = wq4[(c * 3 + kh) * 3 + kw];        // uniform -> SGPR
        #pragma unroll
        for (int p = 0; p < 4; ++p) {
          int4 xv = xr[p + kh];
          int a = acc[p][c];
          a = dot4(xv.x, wv.x, a);
          a = dot4(xv.y, wv.y, a);
          a = dot4(xv.z, wv.z, a);
          a = dot4(xv.w, wv.w, a);
          acc[p][c] = a;
        }
      }
    }
  }
}

// ---- strip staging: 6 full-width xq rows, coalesced; zero row/col pads ----
__device__ __forceinline__ void stage_strip(const int4* __restrict__ xq,
                                            int4* sXs, int n, int r0, int tid) {
  #pragma unroll
  for (int j = 0; j < 6; ++j) {
    int g = r0 - 1 + j;
    if (tid < 224) {
      int4 v = {0, 0, 0, 0};
      if ((unsigned)g < 224u) v = xq[(n * 224 + g) * 224 + tid];
      sXs[j * 226 + 1 + tid] = v;
    } else if (tid < 226) {
      int4 z = {0, 0, 0, 0};
      sXs[j * 226 + ((tid == 224) ? 0 : 225)] = z;   // left / right pad col
    }
  }
}

// ---------------- D1: absmax(x) per block + weight quant in block 0 ----------------
// Verified (Round 2). No atomics: block b writes bmax[b]; consumers reduce.
__global__ __launch_bounds__(256) void k_absmax_wq(const float* __restrict__ x,
                                                   const float* __restrict__ w,
                                                   char* __restrict__ ws) {
  __shared__ float red[4];
  __shared__ float s_sw;
  float* hdr_f = (float*)ws;
  float* bmax = (float*)(ws + WS_BMAX);
  int* wq = (int*)(ws + WS_WQ);
  const int tid = threadIdx.x;

  const float4* x4 = (const float4*)x;
  float m = 0.0f;
  for (int i = blockIdx.x * 256 + tid; i < NELEM / 4; i += ABS_GRID * 256) {
    float4 v = x4[i];
    m = fmaxf(m, fmaxf(fmaxf(fabsf(v.x), fabsf(v.y)),
                       fmaxf(fabsf(v.z), fabsf(v.w))));
  }
  #pragma unroll
  for (int off = 32; off; off >>= 1) m = fmaxf(m, __shfl_down(m, off, 64));
  if ((tid & 63) == 0) red[tid >> 6] = m;
  __syncthreads();
  if (tid == 0)
    bmax[blockIdx.x] = fmaxf(fmaxf(red[0], red[1]), fmaxf(red[2], red[3]));

  if (blockIdx.x == 0) {                             // weight quant (verified)
    __syncthreads();                                 // red[] reuse
    float mw = 0.0f;
    for (int i = tid; i < 2304; i += 256) mw = fmaxf(mw, fabsf(w[i]));
    #pragma unroll
    for (int off = 32; off; off >>= 1) mw = fmaxf(mw, __shfl_down(mw, off, 64));
    if ((tid & 63) == 0) red[tid >> 6] = mw;
    __syncthreads();
    if (tid == 0) {
      float sw = fmaxf(fmaxf(red[0], red[1]), fmaxf(red[2], red[3])) / QP;
      hdr_f[1] = sw;
      s_sw = sw;
    }
    __syncthreads();
    float sw = s_sw;
    // pack: wq[(cout*9 + kh*3+kw)*4 + c4], byte j of dword = cin 4*c4+j
    for (int i = tid; i < 576; i += 256) {
      int cout = i / 36; int r = i - cout * 36;
      int tap = r >> 2;  int c4 = r & 3;
      int kh = tap / 3, kw = tap - kh * 3;
      unsigned bits = 0;
      #pragma unroll
      for (int j = 0; j < 4; ++j) {
        int cin = c4 * 4 + j;
        float v = w[((cout * 16 + cin) * 3 + kh) * 3 + kw];
        int q = (int)rintf(v / sw);                  // rint = round-half-even
        q = max(-127, min(127, q));
        bits |= ((unsigned)(q & 0xff)) << (8 * j);
      }
      wq[i] = (int)bits;
    }
  }
}

// ---------------- D2: quantize x -> NHWC cin-packed int8 (streaming) ----------------
// Verified Round-0 body + verified Round-2 bmax->sx prologue.
__global__ __launch_bounds__(256) void k_quant_x(const float* __restrict__ x,
                                                 char* __restrict__ ws) {
  __shared__ float sRed4[4];
  const float* __restrict__ bmax = (const float*)(ws + WS_BMAX);
  float* hdr_f = (float*)ws;
  int4* xq = (int4*)(ws + WS_XQ);
  const int tid = threadIdx.x;

  float m = 0.0f;
  for (int i = tid; i < ABS_GRID; i += 256) m = fmaxf(m, bmax[i]);
  #pragma unroll
  for (int off = 32; off; off >>= 1) m = fmaxf(m, __shfl_down(m, off, 64));
  if ((tid & 63) == 0) sRed4[tid >> 6] = m;
  __syncthreads();
  const float sx =
      fmaxf(fmaxf(sRed4[0], sRed4[1]), fmaxf(sRed4[2], sRed4[3])) / QP;
  if (blockIdx.x == 0 && tid == 0) hdr_f[2] = sx;    // for k_finalize

  int t = blockIdx.x * 256 + tid;                    // grid 1568*256 = NPIX/4
  int p0 = t * 4;
  int n = p0 / HW2;                                  // HW2 % 4 == 0: no n-crossing
  int hw = p0 - n * HW2;
  const float4* xb = (const float4*)(x + (size_t)n * 16 * HW2 + hw);
  unsigned comp[4][4];
  #pragma unroll
  for (int j = 0; j < 4; ++j)
    #pragma unroll
    for (int k = 0; k < 4; ++k) comp[j][k] = 0u;
  #pragma unroll
  for (int c = 0; c < 16; ++c) {
    float4 vc = xb[c * (HW2 / 4)];
    float f[4] = {vc.x, vc.y, vc.z, vc.w};
    #pragma unroll
    for (int j = 0; j < 4; ++j) {
      int q = (int)rintf(f[j] / sx);                 // f32 div, matches ref
      q = max(-127, min(127, q));
      comp[j][c >> 2] |= ((unsigned)(q & 0xff)) << (8 * (c & 3));
    }
  }
  #pragma unroll
  for (int j = 0; j < 4; ++j) {
    int4 v;
    v.x = (int)comp[j][0]; v.y = (int)comp[j][1];
    v.z = (int)comp[j][2]; v.w = (int)comp[j][3];
    xq[p0 + j] = v;
  }
}

// ---------------- D3: strip conv, stats pass ----------------
__global__ __launch_bounds__(256) void k_conv_stats(const char* __restrict__ ws,
                                                    float* __restrict__ partials) {
  __shared__ int4 sXs[6 * 226];                      // 21696 B; aliased as f32 below
  __shared__ float sRedS[4][16];
  __shared__ float sRedQ[4][16];
  const int4* __restrict__ xq = (const int4*)(ws + WS_XQ);
  const int4* __restrict__ wq4 = (const int4*)(ws + WS_WQ);

  const int tid = threadIdx.x;
  const int b = blockIdx.x;
  const int n = b / NRG, rg = b - n * NRG;
  const int r0 = rg * 4;

  stage_strip(xq, sXs, n, r0, tid);
  __syncthreads();

  int acc[4][16];
  #pragma unroll
  for (int p = 0; p < 4; ++p)
    #pragma unroll
    for (int c = 0; c < 16; ++c) acc[p][c] = 0;
  if (tid < 224) conv_strip(sXs, wq4, tid, acc);     // lanes 224..255 stay zero

  // ---- stats epilogue: LDS transpose (stride 257) + EXACT reduction ----
  // Thread tid sums row cc = tid&15 over its OWN column group (tid>>4)*16..+15
  // (bijective over 16 rows x 16 groups); shfl_xor(16/32) folds each wave's 4
  // groups; the cross-wave sRedS/Q sum covers all 256 columns exactly once.
  // NOTE: the inherited baseline index `(seg&3)*16` read only cols 0..63 (x4 =
  // unbiased 1/4 sample in the tile layout, but an 8/7-biased sample in the
  // 224-active strip layout -> Round-3 absmax 0.34). This version is exact.
  float* sR = (float*)sXs;                           // 16448 B used
  int wv_ = tid >> 6, cc = tid & 15;
  const int colbase = (tid >> 4) << 4;               // tid & ~15
  __syncthreads();                                   // all sXs reads done
  #pragma unroll
  for (int c = 0; c < 16; ++c) {
    int si = acc[0][c] + acc[1][c] + acc[2][c] + acc[3][c];  // exact in int32
    sR[c * 257 + tid] = (float)si;
  }
  __syncthreads();
  {
    float ps = 0.0f;
    #pragma unroll
    for (int j = 0; j < 16; ++j) ps += sR[cc * 257 + colbase + j];
    ps += __shfl_xor(ps, 16, 64);
    ps += __shfl_xor(ps, 32, 64);
    if ((tid & 63) < 16) sRedS[wv_][cc] = ps;
  }
  __syncthreads();
  #pragma unroll
  for (int c = 0; c < 16; ++c) {
    float f0 = (float)acc[0][c], f1 = (float)acc[1][c];
    float f2 = (float)acc[2][c], f3 = (float)acc[3][c];
    sR[c * 257 + tid] = f0 * f0 + f1 * f1 + f2 * f2 + f3 * f3;
  }
  __syncthreads();
  {
    float pq = 0.0f;
    #pragma unroll
    for (int j = 0; j < 16; ++j) pq += sR[cc * 257 + colbase + j];
    pq += __shfl_xor(pq, 16, 64);
    pq += __shfl_xor(pq, 32, 64);
    if ((tid & 63) < 16) sRedQ[wv_][cc] = pq;
  }
  __syncthreads();
  if (tid < 32) {
    int c = tid & 15;
    float t;
    if (tid < 16) t = sRedS[0][c] + sRedS[1][c] + sRedS[2][c] + sRedS[3][c];
    else          t = sRedQ[0][c] + sRedQ[1][c] + sRedQ[2][c] + sRedQ[3][c];
    partials[b * 32 + tid] = t;
  }
}

// ---------------- D4: finalize BN coefficients (verified, 56-group variant) ----------------
__global__ void k_finalize(const float* __restrict__ partials,
                           const float* __restrict__ gamma,
                           const float* __restrict__ beta,
                           float* __restrict__ hdr_f) {
  __shared__ double sdd[256][4];
  __shared__ double sfin[32];
  int t = threadIdx.x;
  const float4* p4 = (const float4*)partials;        // 14336 float4s
  double d0 = 0, d1 = 0, d2 = 0, d3 = 0;
  #pragma unroll 8
  for (int k = 0; k < 56; ++k) {                     // 56*256*4 = 57344 floats
    float4 v = p4[t + 256 * k];
    d0 += (double)v.x; d1 += (double)v.y; d2 += (double)v.z; d3 += (double)v.w;
  }
  // stat id of d_j is ((4*t) % 32) + j  (1024 == 0 mod 32 -> constant over k)
  sdd[t][0] = d0; sdd[t][1] = d1; sdd[t][2] = d2; sdd[t][3] = d3;
  __syncthreads();
  if (t < 32) {
    double s = 0.0;
    #pragma unroll 8
    for (int i = 0; i < 32; ++i) s += sdd[(t >> 2) + 8 * i][t & 3];
    sfin[t] = s;
  }
  __syncthreads();
  if (t < 16) {
    float sf = hdr_f[2] * hdr_f[1];                  // sx * sw (f32, verified)
    double s = (double)sf;
    const double M = (double)NPIX;
    double mean = s * sfin[t] / M;
    double ey2 = s * s * sfin[16 + t] / M;
    double var = ey2 - mean * mean;                  // biased var, matches jnp.var
    double inv = (double)gamma[t] / sqrt(var + 1e-5);
    hdr_f[16 + t] = (float)(s * inv);                // A: applied to raw int acc
    hdr_f[32 + t] = (float)((double)beta[t] - mean * inv);  // B
  }
}

// ---------------- D5: strip conv, output pass ----------------
__global__ __launch_bounds__(256) void k_conv_out(const char* __restrict__ ws,
                                                  float* __restrict__ out) {
  __shared__ int4 sXs[6 * 226];
  const int4* __restrict__ xq = (const int4*)(ws + WS_XQ);
  const int4* __restrict__ wq4 = (const int4*)(ws + WS_WQ);
  const float* hdr_f = (const float*)ws;

  const int tid = threadIdx.x;
  const int b = blockIdx.x;
  const int n = b / NRG, rg = b - n * NRG;
  const int r0 = rg * 4;

  stage_strip(xq, sXs, n, r0, tid);
  __syncthreads();

  if (tid < 224) {
    int acc[4][16];
    #pragma unroll
    for (int p = 0; p < 4; ++p)
      #pragma unroll
      for (int c = 0; c < 16; ++c) acc[p][c] = 0;
    conv_strip(sXs, wq4, tid, acc);

    #pragma unroll
    for (int c = 0; c < 16; ++c) {
      float A = hdr_f[16 + c], B = hdr_f[32 + c];    // uniform -> SGPR
      #pragma unroll
      for (int p = 0; p < 4; ++p) {
        float y = fmaf((float)acc[p][c], A, B);
        y = fminf(fmaxf(y, 0.0f), 6.0f);
        out[((n * 16 + c) * 224 + (r0 + p)) * 224 + tid] = y;
      }
    }
  }
}

extern "C" void kernel_launch(void* const* d_in, const int* in_sizes, int n_in,
                              void* d_out, int out_size, void* d_ws, size_t ws_size,
                              hipStream_t stream) {
  const float* x = (const float*)d_in[0];
  const float* w = (const float*)d_in[1];
  const float* gamma = (const float*)d_in[2];
  const float* beta = (const float*)d_in[3];
  float* out = (float*)d_out;
  char* ws = (char*)d_ws;
  float* partials = (float*)(ws + WS_PART);

  k_absmax_wq<<<ABS_GRID, 256, 0, stream>>>(x, w, ws);
  k_quant_x<<<1568, 256, 0, stream>>>(x, ws);
  k_conv_stats<<<NBLK_CONV, 256, 0, stream>>>(ws, partials);
  k_finalize<<<1, 256, 0, stream>>>(partials, gamma, beta, (float*)ws);
  k_conv_out<<<NBLK_CONV, 256, 0, stream>>>(ws, out);
}